// Round 9
// baseline (1338.651 us; speedup 1.0000x reference)
//
#include <hip/hip_runtime.h>
#include <stdint.h>

#define NTOK 16384
#define HD   1024
#define SD   256
#define NE   8

typedef short bf16x8 __attribute__((ext_vector_type(8)));
typedef _Float16 f16x8 __attribute__((ext_vector_type(8)));
typedef float f32x4 __attribute__((ext_vector_type(4)));
typedef unsigned short u16;
typedef unsigned short u16x8 __attribute__((ext_vector_type(8)));

__device__ __forceinline__ u16 f2bf(float f) {
  union { float f; unsigned u; } v; v.f = f;
  return (u16)((v.u + 0x7fffu + ((v.u >> 16) & 1u)) >> 16);
}

__device__ __forceinline__ void gload16(const void* g, void* l) {
  __builtin_amdgcn_global_load_lds((const __attribute__((address_space(1))) void*)g,
                                   (__attribute__((address_space(3))) void*)l,
                                   16, 0, 0);
}

// meta layout (ints): [0..7] counts, [8..15] cursors, [16..24] offsets,
// [25] ntiles, [26] logits-done counter, [32..191] tile_e, [192..351] tile_row0,
// [352..511] tile_end

// LDS chunk-XOR swizzle (all 3 GEMMs): tile rows are 32 u16 = 4 chunks of 16B.
// LDS[row][slot] holds global chunk (slot ^ ((row>>1)&3)). Staging lane l reads
// global chunk (l&3)^((l>>3)&3) of row l>>2 -> each 4-lane group still covers
// one contiguous 64B row segment (VMEM coalescing identical) and the linear
// gload_lds dest produces the swizzled layout. Fragment read lane l uses slot
// (l>>4)^((l>>1)&3): conflict-free ds_read_b128 (verified: conflicts 8.7M -> 0).
// K-loops fully unrolled (r8: VALU overhead -> compile-time offsets; -25us).
// r9: rgemm re-tiled to gemm1's exact shape (128-col N-tiles, 16 MFMA/step,
// grid 256) halving its block-step count; perm_kernel fused into gatherx.

// ---------------- Fused prep: aprep (8192 blk) + bprep (64 blk) + tconv (4608 blk) ----------------
__global__ __launch_bounds__(256) void prep_kernel(
    const float* __restrict__ ue, _Float16* __restrict__ aP,
    const float* __restrict__ sw1, _Float16* __restrict__ bP,
    const float* __restrict__ ew1, const float* __restrict__ ew2,
    const float* __restrict__ uw1, const float* __restrict__ uw2,
    u16* __restrict__ ew1t, u16* __restrict__ ew2t,
    u16* __restrict__ uw1t, u16* __restrict__ uw2t) {
  const int bid = blockIdx.x;
  const int tid = threadIdx.x;
  if (bid < 8192) {
    // --- aprep: ue f32 -> A' = [hi | lo] fp16, row stride 2048 ---
    const int t = bid * 256 + tid;
    const int p = t >> 7;
    const int h = (t & 127) << 3;
    const float* s = ue + ((size_t)p << 10) + h;
    const float4 a = *(const float4*)s;
    const float4 b = *(const float4*)(s + 4);
    float v[8] = {a.x, a.y, a.z, a.w, b.x, b.y, b.z, b.w};
    f16x8 hi, lo;
#pragma unroll
    for (int j = 0; j < 8; ++j) {
      const _Float16 h16 = (_Float16)v[j];
      hi[j] = h16;
      lo[j] = (_Float16)(v[j] - (float)h16);
    }
    _Float16* d = aP + ((size_t)p << 11) + h;
    *(f16x8*)d = hi;
    *(f16x8*)(d + 1024) = lo;
    return;
  }
  __shared__ float tb[64][65];
  if (bid < 8256) {
    // --- bprep: sw1 [1024][256] f32 -> B' [256][3072] fp16 = [hi|lo|hi] ---
    const int b = bid - 8192;
    const int c0 = (b & 3) << 6;
    const int r0 = (b >> 2) << 6;
    {
      const int lr = tid >> 2, q = (tid & 3) << 4;
      const float* s = sw1 + (size_t)(r0 + lr) * SD + c0 + q;
#pragma unroll
      for (int j = 0; j < 16; j += 4) {
        const float4 v = *(const float4*)(s + j);
        tb[lr][q + j] = v.x; tb[lr][q + j + 1] = v.y;
        tb[lr][q + j + 2] = v.z; tb[lr][q + j + 3] = v.w;
      }
    }
    __syncthreads();
    const int lc = tid >> 2, rq = (tid & 3) << 4;
    f16x8 hi0, hi1, lo0, lo1;
#pragma unroll
    for (int j = 0; j < 8; ++j) {
      const float v0 = tb[rq + j][lc];
      const _Float16 h0 = (_Float16)v0;
      hi0[j] = h0; lo0[j] = (_Float16)(v0 - (float)h0);
      const float v1 = tb[rq + 8 + j][lc];
      const _Float16 h1 = (_Float16)v1;
      hi1[j] = h1; lo1[j] = (_Float16)(v1 - (float)h1);
    }
    _Float16* d = bP + (size_t)(c0 + lc) * 3072 + r0 + rq;
    *(f16x8*)d = hi0;           *(f16x8*)(d + 8) = hi1;
    *(f16x8*)(d + 1024) = lo0;  *(f16x8*)(d + 1032) = lo1;
    *(f16x8*)(d + 2048) = hi0;  *(f16x8*)(d + 2056) = hi1;
    return;
  }
  // --- tconv: transpose+convert 1024x1024 f32 -> bf16, 18 matrices ---
  const int c = bid - 8256;
  const int m = c >> 8;
  const int t2 = c & 255;
  const int c0 = (t2 & 15) << 6;
  const int r0 = (t2 >> 4) << 6;
  const size_t msz = (size_t)HD * HD;
  const float* src; u16* dst;
  if (m < 8)       { src = ew1 + (size_t)m * msz;       dst = ew1t + (size_t)m * msz; }
  else if (m < 16) { src = ew2 + (size_t)(m - 8) * msz; dst = ew2t + (size_t)(m - 8) * msz; }
  else if (m == 16){ src = uw1;                          dst = uw1t; }
  else             { src = uw2;                          dst = uw2t; }
  {
    const int lr = tid >> 2, q = (tid & 3) << 4;
    const float* s = src + (size_t)(r0 + lr) * HD + c0 + q;
#pragma unroll
    for (int j = 0; j < 16; j += 4) {
      const float4 v = *(const float4*)(s + j);
      tb[lr][q + j] = v.x; tb[lr][q + j + 1] = v.y;
      tb[lr][q + j + 2] = v.z; tb[lr][q + j + 3] = v.w;
    }
  }
  __syncthreads();
  {
    const int lc = tid >> 2, rq = (tid & 3) << 4;
    u16x8 o0, o1;
#pragma unroll
    for (int j = 0; j < 8; ++j) o0[j] = f2bf(tb[rq + j][lc]);
#pragma unroll
    for (int j = 0; j < 8; ++j) o1[j] = f2bf(tb[rq + 8 + j][lc]);
    u16* d = dst + (size_t)(c0 + lc) * HD + r0 + rq;
    *(u16x8*)d = o0;
    *(u16x8*)(d + 8) = o1;
  }
}

// ---------------- Router GEMM: 128x128 tiles (gemm1 shape), 16 MFMA/step, grid 256 ----------------
__global__ __launch_bounds__(256) void rgemm_kernel(
    const _Float16* __restrict__ aP, const _Float16* __restrict__ bP,
    const float* __restrict__ sb1, float* __restrict__ hidden) {
  const int p = blockIdx.x;
  const int L = (p & 7) * 32 + (p >> 3);  // XCD-bijective over 256
  const int jt = L & 1;                   // 128-col tile
  const int row0 = (L >> 1) << 7;         // 128-row tile

  __shared__ _Float16 sA[2][128 * 32];
  __shared__ _Float16 sB[2][128 * 32];

  const int tid = threadIdx.x, lane = tid & 63, wave = tid >> 6;
  const int wr = (wave >> 1) << 6, wc = (wave & 1) << 6;
  const int smrow = tid >> 2, skoff = (((tid & 3) ^ ((tid >> 3) & 3)) << 3);
  const _Float16* ar0 = aP + ((size_t)(row0 + smrow) << 11) + skoff;
  const _Float16* ar1 = aP + ((size_t)(row0 + smrow + 64) << 11) + skoff;
  const _Float16* br0 = bP + (size_t)((jt << 7) + smrow) * 3072 + skoff;
  const _Float16* br1 = bP + (size_t)((jt << 7) + smrow + 64) * 3072 + skoff;
  const int ldsoff = wave << 10;

  f32x4 acc[4][4];
#pragma unroll
  for (int i = 0; i < 4; ++i)
#pragma unroll
    for (int j = 0; j < 4; ++j) acc[i][j] = (f32x4){0.f, 0.f, 0.f, 0.f};

  gload16(ar0, (char*)sA[0] + ldsoff);
  gload16(ar1, (char*)sA[0] + 4096 + ldsoff);
  gload16(br0, (char*)sB[0] + ldsoff);
  gload16(br1, (char*)sB[0] + 4096 + ldsoff);

  const int sl = (((lane >> 4) ^ ((lane >> 1) & 3)) << 3);
  const int afrag = (wr + (lane & 15)) * 32 + sl;
  const int bfrag = (wc + (lane & 15)) * 32 + sl;

#pragma unroll
  for (int ks = 0; ks < 96; ++ks) {
    const int buf = ks & 1;
    __syncthreads();
    if (ks + 1 < 96) {
      const int k1 = ks + 1;
      // A' k-offset: term order hiA*hiB (0-31), hiA*loB (32-63), loA*hiB (64-95)
      const int pa = (k1 < 64) ? ((k1 & 31) << 5) : (1024 + ((k1 - 64) << 5));
      gload16(ar0 + pa, (char*)sA[buf ^ 1] + ldsoff);
      gload16(ar1 + pa, (char*)sA[buf ^ 1] + 4096 + ldsoff);
      gload16(br0 + (k1 << 5), (char*)sB[buf ^ 1] + ldsoff);
      gload16(br1 + (k1 << 5), (char*)sB[buf ^ 1] + 4096 + ldsoff);
    }
    f16x8 av[4], bv[4];
#pragma unroll
    for (int f = 0; f < 4; ++f) {
      av[f] = *(const f16x8*)&sA[buf][afrag + f * 512];
      bv[f] = *(const f16x8*)&sB[buf][bfrag + f * 512];
    }
#pragma unroll
    for (int i = 0; i < 4; ++i)
#pragma unroll
      for (int j = 0; j < 4; ++j)
        acc[i][j] = __builtin_amdgcn_mfma_f32_16x16x32_f16(av[i], bv[j], acc[i][j], 0, 0, 0);
  }

  const int lc = lane & 15, lr4 = (lane >> 4) << 2;
#pragma unroll
  for (int j = 0; j < 4; ++j) {
    const int c = (jt << 7) + wc + (j << 4) + lc;
    const float bias = sb1[c & 255];
#pragma unroll
    for (int i = 0; i < 4; ++i) {
      const int rl = wr + (i << 4) + lr4;
#pragma unroll
      for (int q = 0; q < 4; ++q)
        hidden[((size_t)(row0 + rl + q) << 8) + (c & 255)] = fmaxf(acc[i][j][q] + bias, 0.f);
    }
  }
}

// ---------------- Logits layer-2 + argmax + histogram + fused scan (last block) ----------------
__global__ __launch_bounds__(256) void logits_kernel(
    const float* __restrict__ hidden, const float* __restrict__ sw2,
    const float* __restrict__ sb2, int* __restrict__ routes, int* meta) {
  __shared__ float logl[32][8];
  const int tid = threadIdx.x;
  const int tok0 = blockIdx.x << 5;
  const int tl = tid >> 3, e2 = tid & 7;
  const float* hp = hidden + ((size_t)(tok0 + tl) << 8);
  float a0 = 0.f, a1 = 0.f, a2 = 0.f, a3 = 0.f;
  for (int q = 0; q < SD; q += 8) {
    const float4 h0 = *(const float4*)&hp[q];
    const float4 h1 = *(const float4*)&hp[q + 4];
    a0 = fmaf(h0.x, sw2[((q + 0) << 3) + e2], a0);
    a1 = fmaf(h0.y, sw2[((q + 1) << 3) + e2], a1);
    a2 = fmaf(h0.z, sw2[((q + 2) << 3) + e2], a2);
    a3 = fmaf(h0.w, sw2[((q + 3) << 3) + e2], a3);
    a0 = fmaf(h1.x, sw2[((q + 4) << 3) + e2], a0);
    a1 = fmaf(h1.y, sw2[((q + 5) << 3) + e2], a1);
    a2 = fmaf(h1.z, sw2[((q + 6) << 3) + e2], a2);
    a3 = fmaf(h1.w, sw2[((q + 7) << 3) + e2], a3);
  }
  logl[tl][e2] = (a0 + a1) + (a2 + a3) + sb2[e2];
  __syncthreads();
  if (tid < 32) {
    float best = logl[tid][0]; int be = 0;
#pragma unroll
    for (int e = 1; e < 8; ++e) {
      const float v = logl[tid][e];
      if (v > best) { best = v; be = e; }
    }
    routes[tok0 + tid] = be;
    atomicAdd(&meta[be], 1);
  }
  // last-block-done: fused scan (replaces scan_kernel launch)
  __syncthreads();
  if (tid == 0) {
    __threadfence();
    const int done = atomicAdd(&meta[26], 1);
    if (done == (int)gridDim.x - 1) {
      int cnt[NE];
#pragma unroll
      for (int e = 0; e < NE; ++e) cnt[e] = atomicAdd(&meta[e], 0);
      int off = 0;
      for (int e = 0; e < NE; ++e) { meta[16 + e] = off; off += cnt[e]; }
      meta[24] = off;
      int nt = 0;
      for (int e = 0; e < NE; ++e) {
        const int s = meta[16 + e], en = meta[16 + e + 1];
        for (int r0 = s; r0 < en; r0 += 128) {
          meta[32 + nt] = e; meta[192 + nt] = r0; meta[352 + nt] = en; ++nt;
        }
      }
      meta[25] = nt;
      __threadfence();
    }
  }
}

// ---------------- Fused perm + gather: token -> grouped pos, copy row, write perm ----------------
__global__ __launch_bounds__(256) void gatherx_kernel(
    const float* __restrict__ x, const int* __restrict__ routes,
    int* meta, int* __restrict__ perm, u16* __restrict__ xg) {
  __shared__ int pos_s[2];
  const int tid = threadIdx.x;
  const int half = tid >> 7;                 // 0/1: token within block
  const int b = (blockIdx.x << 1) + half;    // token id
  if ((tid & 127) == 0) {
    const int r = routes[b];
    const int pos = meta[16 + r] + atomicAdd(&meta[8 + r], 1);
    perm[pos] = b;
    pos_s[half] = pos;
  }
  __syncthreads();
  const int pos = pos_s[half];
  const int j = (tid & 127) << 3;
  const float* s = &x[((size_t)b << 10) + j];
  const float4 a = *(const float4*)s;
  const float4 c = *(const float4*)(s + 4);
  u16x8 o;
  o[0] = f2bf(a.x); o[1] = f2bf(a.y); o[2] = f2bf(a.z); o[3] = f2bf(a.w);
  o[4] = f2bf(c.x); o[5] = f2bf(c.y); o[6] = f2bf(c.z); o[7] = f2bf(c.w);
  *(u16x8*)&xg[((size_t)pos << 10) + j] = o;
}

// ---------------- GEMM1: hid[p][0:2048] = relu(xg[p] @ [ew1[e] | uw1] + eb1[e]/ub1) ----------------
__global__ __launch_bounds__(256) void gemm1_kernel(
    const u16* __restrict__ xg, const u16* __restrict__ ew1t,
    const u16* __restrict__ uw1t, const float* __restrict__ eb1,
    const float* __restrict__ ub1, const int* __restrict__ meta,
    u16* __restrict__ hid) {
  const int nt = meta[25];
  // XCD-chunked, mt-major: grid 2160 = 16 jt x 135 mt
  const int pb = blockIdx.x;
  const int L = (pb & 7) * 270 + (pb >> 3);
  const int mt = L >> 4;
  const int jt = L & 15;
  if (mt >= nt) return;
  const int e = meta[32 + mt], row0 = meta[192 + mt], gend = meta[352 + mt];
  const u16* wbase = (jt < 8)
      ? ew1t + ((size_t)e << 20) + ((size_t)(jt << 7) << 10)
      : uw1t + ((size_t)((jt - 8) << 7) << 10);

  __shared__ u16 sA[2][128 * 32];
  __shared__ u16 sB[2][128 * 32];

  const int tid = threadIdx.x;
  const int lane = tid & 63;
  const int wave = tid >> 6;
  const int wr = (wave >> 1) << 6;
  const int wc = (wave & 1) << 6;

  const int smrow = tid >> 2;
  const int skoff = (((tid & 3) ^ ((tid >> 3) & 3)) << 3);
  const u16* ap0 = xg + (((size_t)(row0 + smrow)) << 10) + skoff;
  const u16* ap1 = xg + (((size_t)(row0 + smrow + 64)) << 10) + skoff;
  const u16* bp0 = wbase + (((size_t)smrow) << 10) + skoff;
  const u16* bp1 = wbase + (((size_t)(smrow + 64)) << 10) + skoff;
  const int ldsoff = wave << 10;

  f32x4 acc[4][4];
#pragma unroll
  for (int i = 0; i < 4; ++i)
#pragma unroll
    for (int j = 0; j < 4; ++j) acc[i][j] = (f32x4){0.f, 0.f, 0.f, 0.f};

  gload16(ap0, (char*)sA[0] + ldsoff);
  gload16(ap1, (char*)sA[0] + 4096 + ldsoff);
  gload16(bp0, (char*)sB[0] + ldsoff);
  gload16(bp1, (char*)sB[0] + 4096 + ldsoff);

  const int sl = (((lane >> 4) ^ ((lane >> 1) & 3)) << 3);
  const int afrag = (wr + (lane & 15)) * 32 + sl;
  const int bfrag = (wc + (lane & 15)) * 32 + sl;

#pragma unroll
  for (int ks = 0; ks < 32; ++ks) {
    const int buf = ks & 1;
    __syncthreads();
    if (ks + 1 < 32) {
      const int k1 = (ks + 1) << 5;
      gload16(ap0 + k1, (char*)sA[buf ^ 1] + ldsoff);
      gload16(ap1 + k1, (char*)sA[buf ^ 1] + 4096 + ldsoff);
      gload16(bp0 + k1, (char*)sB[buf ^ 1] + ldsoff);
      gload16(bp1 + k1, (char*)sB[buf ^ 1] + 4096 + ldsoff);
    }
    bf16x8 av[4], bv[4];
#pragma unroll
    for (int f = 0; f < 4; ++f) {
      av[f] = *(const bf16x8*)&sA[buf][afrag + f * 512];
      bv[f] = *(const bf16x8*)&sB[buf][bfrag + f * 512];
    }
#pragma unroll
    for (int i = 0; i < 4; ++i)
#pragma unroll
      for (int j = 0; j < 4; ++j)
        acc[i][j] = __builtin_amdgcn_mfma_f32_16x16x32_bf16(av[i], bv[j], acc[i][j], 0, 0, 0);
  }

  const int lc = lane & 15;
  const int lr4 = (lane >> 4) << 2;
#pragma unroll
  for (int j = 0; j < 4; ++j) {
    const int c = (jt << 7) + wc + (j << 4) + lc;
    const float bias = (c < 1024) ? eb1[(e << 10) + c] : ub1[c - 1024];
#pragma unroll
    for (int i = 0; i < 4; ++i) {
      const int rl = wr + (i << 4) + lr4;
#pragma unroll
      for (int q = 0; q < 4; ++q) {
        const int p = row0 + rl + q;
        if (p < gend) hid[((size_t)p << 11) + c] = f2bf(fmaxf(acc[i][j][q] + bias, 0.f));
      }
    }
  }
}

// ---------------- GEMM2: out[perm[p]][c] = hid[p] @ [ew2[e]; uw2] + eb2[e] + ub2 ----------------
__global__ __launch_bounds__(256) void gemm2_kernel(
    const u16* __restrict__ hid, const u16* __restrict__ ew2t,
    const u16* __restrict__ uw2t, const float* __restrict__ eb2,
    const float* __restrict__ ub2, const int* __restrict__ meta,
    const int* __restrict__ perm, float* __restrict__ out) {
  const int nt = meta[25];
  // XCD-chunked, mt-major: grid 1080 = 8 jt x 135 mt
  const int pb = blockIdx.x;
  const int L = (pb & 7) * 135 + (pb >> 3);
  const int mt = L >> 3;
  const int jt = L & 7;
  if (mt >= nt) return;
  const int e = meta[32 + mt], row0 = meta[192 + mt], gend = meta[352 + mt];
  const int n0 = jt << 7;

  __shared__ u16 sA[2][128 * 32];
  __shared__ u16 sB[2][128 * 32];

  const int tid = threadIdx.x;
  const int lane = tid & 63;
  const int wave = tid >> 6;
  const int wr = (wave >> 1) << 6;
  const int wc = (wave & 1) << 6;

  const int smrow = tid >> 2;
  const int skoff = (((tid & 3) ^ ((tid >> 3) & 3)) << 3);
  const u16* ap0 = hid + (((size_t)(row0 + smrow)) << 11) + skoff;
  const u16* ap1 = hid + (((size_t)(row0 + smrow + 64)) << 11) + skoff;
  const u16* ebase = ew2t + ((size_t)e << 20);
  const size_t brow0 = (((size_t)(n0 + smrow)) << 10) + skoff;
  const size_t brow1 = (((size_t)(n0 + smrow + 64)) << 10) + skoff;
  const int ldsoff = wave << 10;

  f32x4 acc[4][4];
#pragma unroll
  for (int i = 0; i < 4; ++i)
#pragma unroll
    for (int j = 0; j < 4; ++j) acc[i][j] = (f32x4){0.f, 0.f, 0.f, 0.f};

  gload16(ap0, (char*)sA[0] + ldsoff);
  gload16(ap1, (char*)sA[0] + 4096 + ldsoff);
  gload16(ebase + brow0, (char*)sB[0] + ldsoff);
  gload16(ebase + brow1, (char*)sB[0] + 4096 + ldsoff);

  const int sl = (((lane >> 4) ^ ((lane >> 1) & 3)) << 3);
  const int afrag = (wr + (lane & 15)) * 32 + sl;
  const int bfrag = (wc + (lane & 15)) * 32 + sl;

#pragma unroll
  for (int ks = 0; ks < 64; ++ks) {
    const int buf = ks & 1;
    __syncthreads();
    if (ks + 1 < 64) {
      const int k1 = (ks + 1) << 5;
      const u16* bb = (k1 < 1024) ? ebase : uw2t;
      const int kk = k1 & 1023;
      gload16(ap0 + k1, (char*)sA[buf ^ 1] + ldsoff);
      gload16(ap1 + k1, (char*)sA[buf ^ 1] + 4096 + ldsoff);
      gload16(bb + brow0 + kk, (char*)sB[buf ^ 1] + ldsoff);
      gload16(bb + brow1 + kk, (char*)sB[buf ^ 1] + 4096 + ldsoff);
    }
    bf16x8 av[4], bv[4];
#pragma unroll
    for (int f = 0; f < 4; ++f) {
      av[f] = *(const bf16x8*)&sA[buf][afrag + f * 512];
      bv[f] = *(const bf16x8*)&sB[buf][bfrag + f * 512];
    }
#pragma unroll
    for (int i = 0; i < 4; ++i)
#pragma unroll
      for (int j = 0; j < 4; ++j)
        acc[i][j] = __builtin_amdgcn_mfma_f32_16x16x32_bf16(av[i], bv[j], acc[i][j], 0, 0, 0);
  }

  const int lc = lane & 15;
  const int lr4 = (lane >> 4) << 2;
#pragma unroll
  for (int j = 0; j < 4; ++j) {
    const int c = n0 + wc + (j << 4) + lc;
    const float bias = eb2[(e << 10) + c] + ub2[c];
#pragma unroll
    for (int i = 0; i < 4; ++i) {
      const int rl = wr + (i << 4) + lr4;
#pragma unroll
      for (int q = 0; q < 4; ++q) {
        const int p = row0 + rl + q;
        if (p < gend) out[((size_t)perm[p] << 10) + c] = acc[i][j][q] + bias;
      }
    }
  }
}

extern "C" void kernel_launch(void* const* d_in, const int* in_sizes, int n_in,
                              void* d_out, int out_size, void* d_ws, size_t ws_size,
                              hipStream_t stream) {
  const float* x   = (const float*)d_in[0];
  const float* ue  = (const float*)d_in[1];
  const float* sw1 = (const float*)d_in[2];
  const float* sb1 = (const float*)d_in[3];
  const float* sw2 = (const float*)d_in[4];
  const float* sb2 = (const float*)d_in[5];
  const float* ew1 = (const float*)d_in[6];
  const float* eb1 = (const float*)d_in[7];
  const float* ew2 = (const float*)d_in[8];
  const float* eb2 = (const float*)d_in[9];
  const float* uw1 = (const float*)d_in[10];
  const float* ub1 = (const float*)d_in[11];
  const float* uw2 = (const float*)d_in[12];
  const float* ub2 = (const float*)d_in[13];
  float* out = (float*)d_out;

  char* w = (char*)d_ws;
  int* meta = (int*)w;    w += 4096;
  int* routes = (int*)w;  w += NTOK * 4;
  int* perm = (int*)w;    w += NTOK * 4;
  char* region = w;
  u16* xg   = (u16*)region;                                             // 33,816,576 B
  u16* ew1t = (u16*)(region + 33816576ull);                             // 16 MiB
  u16* ew2t = (u16*)(region + 33816576ull + 16777216ull);               // 16 MiB
  u16* uw1t = (u16*)(region + 33816576ull + 2 * 16777216ull);           // 2 MiB
  u16* uw2t = (u16*)(region + 33816576ull + 2 * 16777216ull + 2097152ull);
  u16* hid  = (u16*)(region + 33816576ull + 2 * 16777216ull + 2 * 2097152ull);  // 67,633,152 B
  const size_t region_sz = 33816576ull + 2 * 16777216ull + 2 * 2097152ull + 67633152ull;
  // router-phase aliases live in the (dead-until-gemm1) hid region / xg region:
  _Float16* aP     = (_Float16*)(region + 33816576ull + 2 * 16777216ull + 2 * 2097152ull);
  float* hidden32  = (float*)region;
  _Float16* bP     = (_Float16*)(region + 16777216ull);
  if (135168ull + region_sz > ws_size) return;

  hipMemsetAsync(meta, 0, 4096, stream);
  prep_kernel<<<12864, 256, 0, stream>>>(ue, aP, sw1, bP, ew1, ew2, uw1, uw2,
                                         ew1t, ew2t, uw1t, uw2t);
  rgemm_kernel<<<256, 256, 0, stream>>>(aP, bP, sb1, hidden32);
  logits_kernel<<<NTOK / 32, 256, 0, stream>>>(hidden32, sw2, sb2, routes, meta);
  gatherx_kernel<<<NTOK / 2, 256, 0, stream>>>(x, routes, meta, perm, xg);
  gemm1_kernel<<<2160, 256, 0, stream>>>(xg, ew1t, uw1t, eb1, ub1, meta, hid);
  gemm2_kernel<<<1080, 256, 0, stream>>>(hid, ew2t, uw2t, eb2, ub2, meta, perm, out);
}

// Round 10
// 622.935 us; speedup vs baseline: 2.1489x; 2.1489x over previous
//
#include <hip/hip_runtime.h>
#include <stdint.h>

#define NTOK 16384
#define HD   1024
#define SD   256
#define NE   8

typedef short bf16x8 __attribute__((ext_vector_type(8)));
typedef _Float16 f16x8 __attribute__((ext_vector_type(8)));
typedef float f32x4 __attribute__((ext_vector_type(4)));
typedef unsigned short u16;
typedef unsigned short u16x8 __attribute__((ext_vector_type(8)));

__device__ __forceinline__ u16 f2bf(float f) {
  union { float f; unsigned u; } v; v.f = f;
  return (u16)((v.u + 0x7fffu + ((v.u >> 16) & 1u)) >> 16);
}

__device__ __forceinline__ void gload16(const void* g, void* l) {
  __builtin_amdgcn_global_load_lds((const __attribute__((address_space(1))) void*)g,
                                   (__attribute__((address_space(3))) void*)l,
                                   16, 0, 0);
}

// meta layout (ints): [0..7] counts, [8..15] cursors, [16..24] offsets,
// [25] ntiles, [26] logits-done counter, [32..191] tile_e, [192..351] tile_row0,
// [352..511] tile_end

// LDS chunk-XOR swizzle (all 3 GEMMs): tile rows are 32 u16 = 4 chunks of 16B.
// LDS[row][slot] holds global chunk (slot ^ ((row>>1)&3)). Staging lane l reads
// global chunk (l&3)^((l>>3)&3) of row l>>2 -> each 4-lane group still covers
// one contiguous 64B row segment (VMEM coalescing identical) and the linear
// gload_lds dest produces the swizzled layout. Fragment read lane l uses slot
// (l>>4)^((l>>1)&3): conflict-free ds_read_b128 (verified: conflicts 8.7M -> 0).
// K-loops fully unrolled (r8: -25us). rgemm 128-col tiles (r9, verified).
// r9 LESSON: do NOT fuse the per-token atomic into gatherx -- a barrier right
// after an atomic on a single hot cache line latency-chains 16384 blocks
// (898us). Separate 64-block perm_kernel pipelines the same atomics fine.

// ---------------- Fused prep: aprep (8192 blk) + bprep (64 blk) + tconv (4608 blk) ----------------
__global__ __launch_bounds__(256) void prep_kernel(
    const float* __restrict__ ue, _Float16* __restrict__ aP,
    const float* __restrict__ sw1, _Float16* __restrict__ bP,
    const float* __restrict__ ew1, const float* __restrict__ ew2,
    const float* __restrict__ uw1, const float* __restrict__ uw2,
    u16* __restrict__ ew1t, u16* __restrict__ ew2t,
    u16* __restrict__ uw1t, u16* __restrict__ uw2t) {
  const int bid = blockIdx.x;
  const int tid = threadIdx.x;
  if (bid < 8192) {
    // --- aprep: ue f32 -> A' = [hi | lo] fp16, row stride 2048 ---
    const int t = bid * 256 + tid;
    const int p = t >> 7;
    const int h = (t & 127) << 3;
    const float* s = ue + ((size_t)p << 10) + h;
    const float4 a = *(const float4*)s;
    const float4 b = *(const float4*)(s + 4);
    float v[8] = {a.x, a.y, a.z, a.w, b.x, b.y, b.z, b.w};
    f16x8 hi, lo;
#pragma unroll
    for (int j = 0; j < 8; ++j) {
      const _Float16 h16 = (_Float16)v[j];
      hi[j] = h16;
      lo[j] = (_Float16)(v[j] - (float)h16);
    }
    _Float16* d = aP + ((size_t)p << 11) + h;
    *(f16x8*)d = hi;
    *(f16x8*)(d + 1024) = lo;
    return;
  }
  __shared__ float tb[64][65];
  if (bid < 8256) {
    // --- bprep: sw1 [1024][256] f32 -> B' [256][3072] fp16 = [hi|lo|hi] ---
    const int b = bid - 8192;
    const int c0 = (b & 3) << 6;
    const int r0 = (b >> 2) << 6;
    {
      const int lr = tid >> 2, q = (tid & 3) << 4;
      const float* s = sw1 + (size_t)(r0 + lr) * SD + c0 + q;
#pragma unroll
      for (int j = 0; j < 16; j += 4) {
        const float4 v = *(const float4*)(s + j);
        tb[lr][q + j] = v.x; tb[lr][q + j + 1] = v.y;
        tb[lr][q + j + 2] = v.z; tb[lr][q + j + 3] = v.w;
      }
    }
    __syncthreads();
    const int lc = tid >> 2, rq = (tid & 3) << 4;
    f16x8 hi0, hi1, lo0, lo1;
#pragma unroll
    for (int j = 0; j < 8; ++j) {
      const float v0 = tb[rq + j][lc];
      const _Float16 h0 = (_Float16)v0;
      hi0[j] = h0; lo0[j] = (_Float16)(v0 - (float)h0);
      const float v1 = tb[rq + 8 + j][lc];
      const _Float16 h1 = (_Float16)v1;
      hi1[j] = h1; lo1[j] = (_Float16)(v1 - (float)h1);
    }
    _Float16* d = bP + (size_t)(c0 + lc) * 3072 + r0 + rq;
    *(f16x8*)d = hi0;           *(f16x8*)(d + 8) = hi1;
    *(f16x8*)(d + 1024) = lo0;  *(f16x8*)(d + 1032) = lo1;
    *(f16x8*)(d + 2048) = hi0;  *(f16x8*)(d + 2056) = hi1;
    return;
  }
  // --- tconv: transpose+convert 1024x1024 f32 -> bf16, 18 matrices ---
  const int c = bid - 8256;
  const int m = c >> 8;
  const int t2 = c & 255;
  const int c0 = (t2 & 15) << 6;
  const int r0 = (t2 >> 4) << 6;
  const size_t msz = (size_t)HD * HD;
  const float* src; u16* dst;
  if (m < 8)       { src = ew1 + (size_t)m * msz;       dst = ew1t + (size_t)m * msz; }
  else if (m < 16) { src = ew2 + (size_t)(m - 8) * msz; dst = ew2t + (size_t)(m - 8) * msz; }
  else if (m == 16){ src = uw1;                          dst = uw1t; }
  else             { src = uw2;                          dst = uw2t; }
  {
    const int lr = tid >> 2, q = (tid & 3) << 4;
    const float* s = src + (size_t)(r0 + lr) * HD + c0 + q;
#pragma unroll
    for (int j = 0; j < 16; j += 4) {
      const float4 v = *(const float4*)(s + j);
      tb[lr][q + j] = v.x; tb[lr][q + j + 1] = v.y;
      tb[lr][q + j + 2] = v.z; tb[lr][q + j + 3] = v.w;
    }
  }
  __syncthreads();
  {
    const int lc = tid >> 2, rq = (tid & 3) << 4;
    u16x8 o0, o1;
#pragma unroll
    for (int j = 0; j < 8; ++j) o0[j] = f2bf(tb[rq + j][lc]);
#pragma unroll
    for (int j = 0; j < 8; ++j) o1[j] = f2bf(tb[rq + 8 + j][lc]);
    u16* d = dst + (size_t)(c0 + lc) * HD + r0 + rq;
    *(u16x8*)d = o0;
    *(u16x8*)(d + 8) = o1;
  }
}

// ---------------- Router GEMM: 128x128 tiles (gemm1 shape), 16 MFMA/step, grid 256 ----------------
__global__ __launch_bounds__(256) void rgemm_kernel(
    const _Float16* __restrict__ aP, const _Float16* __restrict__ bP,
    const float* __restrict__ sb1, float* __restrict__ hidden) {
  const int p = blockIdx.x;
  const int L = (p & 7) * 32 + (p >> 3);  // XCD-bijective over 256
  const int jt = L & 1;                   // 128-col tile
  const int row0 = (L >> 1) << 7;         // 128-row tile

  __shared__ _Float16 sA[2][128 * 32];
  __shared__ _Float16 sB[2][128 * 32];

  const int tid = threadIdx.x, lane = tid & 63, wave = tid >> 6;
  const int wr = (wave >> 1) << 6, wc = (wave & 1) << 6;
  const int smrow = tid >> 2, skoff = (((tid & 3) ^ ((tid >> 3) & 3)) << 3);
  const _Float16* ar0 = aP + ((size_t)(row0 + smrow) << 11) + skoff;
  const _Float16* ar1 = aP + ((size_t)(row0 + smrow + 64) << 11) + skoff;
  const _Float16* br0 = bP + (size_t)((jt << 7) + smrow) * 3072 + skoff;
  const _Float16* br1 = bP + (size_t)((jt << 7) + smrow + 64) * 3072 + skoff;
  const int ldsoff = wave << 10;

  f32x4 acc[4][4];
#pragma unroll
  for (int i = 0; i < 4; ++i)
#pragma unroll
    for (int j = 0; j < 4; ++j) acc[i][j] = (f32x4){0.f, 0.f, 0.f, 0.f};

  gload16(ar0, (char*)sA[0] + ldsoff);
  gload16(ar1, (char*)sA[0] + 4096 + ldsoff);
  gload16(br0, (char*)sB[0] + ldsoff);
  gload16(br1, (char*)sB[0] + 4096 + ldsoff);

  const int sl = (((lane >> 4) ^ ((lane >> 1) & 3)) << 3);
  const int afrag = (wr + (lane & 15)) * 32 + sl;
  const int bfrag = (wc + (lane & 15)) * 32 + sl;

#pragma unroll
  for (int ks = 0; ks < 96; ++ks) {
    const int buf = ks & 1;
    __syncthreads();
    if (ks + 1 < 96) {
      const int k1 = ks + 1;
      // A' k-offset: term order hiA*hiB (0-31), hiA*loB (32-63), loA*hiB (64-95)
      const int pa = (k1 < 64) ? ((k1 & 31) << 5) : (1024 + ((k1 - 64) << 5));
      gload16(ar0 + pa, (char*)sA[buf ^ 1] + ldsoff);
      gload16(ar1 + pa, (char*)sA[buf ^ 1] + 4096 + ldsoff);
      gload16(br0 + (k1 << 5), (char*)sB[buf ^ 1] + ldsoff);
      gload16(br1 + (k1 << 5), (char*)sB[buf ^ 1] + 4096 + ldsoff);
    }
    f16x8 av[4], bv[4];
#pragma unroll
    for (int f = 0; f < 4; ++f) {
      av[f] = *(const f16x8*)&sA[buf][afrag + f * 512];
      bv[f] = *(const f16x8*)&sB[buf][bfrag + f * 512];
    }
#pragma unroll
    for (int i = 0; i < 4; ++i)
#pragma unroll
      for (int j = 0; j < 4; ++j)
        acc[i][j] = __builtin_amdgcn_mfma_f32_16x16x32_f16(av[i], bv[j], acc[i][j], 0, 0, 0);
  }

  const int lc = lane & 15, lr4 = (lane >> 4) << 2;
#pragma unroll
  for (int j = 0; j < 4; ++j) {
    const int c = (jt << 7) + wc + (j << 4) + lc;
    const float bias = sb1[c];
#pragma unroll
    for (int i = 0; i < 4; ++i) {
      const int rl = wr + (i << 4) + lr4;
#pragma unroll
      for (int q = 0; q < 4; ++q)
        hidden[((size_t)(row0 + rl + q) << 8) + c] = fmaxf(acc[i][j][q] + bias, 0.f);
    }
  }
}

// ---------------- Logits layer-2 + argmax + histogram + fused scan (last block) ----------------
__global__ __launch_bounds__(256) void logits_kernel(
    const float* __restrict__ hidden, const float* __restrict__ sw2,
    const float* __restrict__ sb2, int* __restrict__ routes, int* meta) {
  __shared__ float logl[32][8];
  const int tid = threadIdx.x;
  const int tok0 = blockIdx.x << 5;
  const int tl = tid >> 3, e2 = tid & 7;
  const float* hp = hidden + ((size_t)(tok0 + tl) << 8);
  float a0 = 0.f, a1 = 0.f, a2 = 0.f, a3 = 0.f;
  for (int q = 0; q < SD; q += 8) {
    const float4 h0 = *(const float4*)&hp[q];
    const float4 h1 = *(const float4*)&hp[q + 4];
    a0 = fmaf(h0.x, sw2[((q + 0) << 3) + e2], a0);
    a1 = fmaf(h0.y, sw2[((q + 1) << 3) + e2], a1);
    a2 = fmaf(h0.z, sw2[((q + 2) << 3) + e2], a2);
    a3 = fmaf(h0.w, sw2[((q + 3) << 3) + e2], a3);
    a0 = fmaf(h1.x, sw2[((q + 4) << 3) + e2], a0);
    a1 = fmaf(h1.y, sw2[((q + 5) << 3) + e2], a1);
    a2 = fmaf(h1.z, sw2[((q + 6) << 3) + e2], a2);
    a3 = fmaf(h1.w, sw2[((q + 7) << 3) + e2], a3);
  }
  logl[tl][e2] = (a0 + a1) + (a2 + a3) + sb2[e2];
  __syncthreads();
  if (tid < 32) {
    float best = logl[tid][0]; int be = 0;
#pragma unroll
    for (int e = 1; e < 8; ++e) {
      const float v = logl[tid][e];
      if (v > best) { best = v; be = e; }
    }
    routes[tok0 + tid] = be;
    atomicAdd(&meta[be], 1);
  }
  // last-block-done: fused scan (replaces scan_kernel launch)
  __syncthreads();
  if (tid == 0) {
    __threadfence();
    const int done = atomicAdd(&meta[26], 1);
    if (done == (int)gridDim.x - 1) {
      int cnt[NE];
#pragma unroll
      for (int e = 0; e < NE; ++e) cnt[e] = atomicAdd(&meta[e], 0);
      int off = 0;
      for (int e = 0; e < NE; ++e) { meta[16 + e] = off; off += cnt[e]; }
      meta[24] = off;
      int nt = 0;
      for (int e = 0; e < NE; ++e) {
        const int s = meta[16 + e], en = meta[16 + e + 1];
        for (int r0 = s; r0 < en; r0 += 128) {
          meta[32 + nt] = e; meta[192 + nt] = r0; meta[352 + nt] = en; ++nt;
        }
      }
      meta[25] = nt;
      __threadfence();
    }
  }
}

// ---------------- Build permutation (token -> grouped position) ----------------
__global__ void perm_kernel(const int* __restrict__ routes, int* meta, int* __restrict__ perm) {
  const int b = blockIdx.x * 256 + threadIdx.x;
  const int r = routes[b];
  const int pos = meta[16 + r] + atomicAdd(&meta[8 + r], 1);
  perm[pos] = b;
}

// ---------------- Gather x rows into grouped order, f32 -> bf16 ----------------
__global__ __launch_bounds__(256) void gatherx_kernel(
    const float* __restrict__ x, const int* __restrict__ perm, u16* __restrict__ xg) {
  const int t = blockIdx.x * 256 + threadIdx.x;
  const int p = t >> 7;
  const int j = (t & 127) << 3;
  const int tok = perm[p];
  const float* s = &x[((size_t)tok << 10) + j];
  const float4 a = *(const float4*)s;
  const float4 b = *(const float4*)(s + 4);
  u16x8 o;
  o[0] = f2bf(a.x); o[1] = f2bf(a.y); o[2] = f2bf(a.z); o[3] = f2bf(a.w);
  o[4] = f2bf(b.x); o[5] = f2bf(b.y); o[6] = f2bf(b.z); o[7] = f2bf(b.w);
  *(u16x8*)&xg[((size_t)p << 10) + j] = o;
}

// ---------------- GEMM1: hid[p][0:2048] = relu(xg[p] @ [ew1[e] | uw1] + eb1[e]/ub1) ----------------
__global__ __launch_bounds__(256) void gemm1_kernel(
    const u16* __restrict__ xg, const u16* __restrict__ ew1t,
    const u16* __restrict__ uw1t, const float* __restrict__ eb1,
    const float* __restrict__ ub1, const int* __restrict__ meta,
    u16* __restrict__ hid) {
  const int nt = meta[25];
  // XCD-chunked, mt-major: grid 2160 = 16 jt x 135 mt
  const int pb = blockIdx.x;
  const int L = (pb & 7) * 270 + (pb >> 3);
  const int mt = L >> 4;
  const int jt = L & 15;
  if (mt >= nt) return;
  const int e = meta[32 + mt], row0 = meta[192 + mt], gend = meta[352 + mt];
  const u16* wbase = (jt < 8)
      ? ew1t + ((size_t)e << 20) + ((size_t)(jt << 7) << 10)
      : uw1t + ((size_t)((jt - 8) << 7) << 10);

  __shared__ u16 sA[2][128 * 32];
  __shared__ u16 sB[2][128 * 32];

  const int tid = threadIdx.x;
  const int lane = tid & 63;
  const int wave = tid >> 6;
  const int wr = (wave >> 1) << 6;
  const int wc = (wave & 1) << 6;

  const int smrow = tid >> 2;
  const int skoff = (((tid & 3) ^ ((tid >> 3) & 3)) << 3);
  const u16* ap0 = xg + (((size_t)(row0 + smrow)) << 10) + skoff;
  const u16* ap1 = xg + (((size_t)(row0 + smrow + 64)) << 10) + skoff;
  const u16* bp0 = wbase + (((size_t)smrow) << 10) + skoff;
  const u16* bp1 = wbase + (((size_t)(smrow + 64)) << 10) + skoff;
  const int ldsoff = wave << 10;

  f32x4 acc[4][4];
#pragma unroll
  for (int i = 0; i < 4; ++i)
#pragma unroll
    for (int j = 0; j < 4; ++j) acc[i][j] = (f32x4){0.f, 0.f, 0.f, 0.f};

  gload16(ap0, (char*)sA[0] + ldsoff);
  gload16(ap1, (char*)sA[0] + 4096 + ldsoff);
  gload16(bp0, (char*)sB[0] + ldsoff);
  gload16(bp1, (char*)sB[0] + 4096 + ldsoff);

  const int sl = (((lane >> 4) ^ ((lane >> 1) & 3)) << 3);
  const int afrag = (wr + (lane & 15)) * 32 + sl;
  const int bfrag = (wc + (lane & 15)) * 32 + sl;

#pragma unroll
  for (int ks = 0; ks < 32; ++ks) {
    const int buf = ks & 1;
    __syncthreads();
    if (ks + 1 < 32) {
      const int k1 = (ks + 1) << 5;
      gload16(ap0 + k1, (char*)sA[buf ^ 1] + ldsoff);
      gload16(ap1 + k1, (char*)sA[buf ^ 1] + 4096 + ldsoff);
      gload16(bp0 + k1, (char*)sB[buf ^ 1] + ldsoff);
      gload16(bp1 + k1, (char*)sB[buf ^ 1] + 4096 + ldsoff);
    }
    bf16x8 av[4], bv[4];
#pragma unroll
    for (int f = 0; f < 4; ++f) {
      av[f] = *(const bf16x8*)&sA[buf][afrag + f * 512];
      bv[f] = *(const bf16x8*)&sB[buf][bfrag + f * 512];
    }
#pragma unroll
    for (int i = 0; i < 4; ++i)
#pragma unroll
      for (int j = 0; j < 4; ++j)
        acc[i][j] = __builtin_amdgcn_mfma_f32_16x16x32_bf16(av[i], bv[j], acc[i][j], 0, 0, 0);
  }

  const int lc = lane & 15;
  const int lr4 = (lane >> 4) << 2;
#pragma unroll
  for (int j = 0; j < 4; ++j) {
    const int c = (jt << 7) + wc + (j << 4) + lc;
    const float bias = (c < 1024) ? eb1[(e << 10) + c] : ub1[c - 1024];
#pragma unroll
    for (int i = 0; i < 4; ++i) {
      const int rl = wr + (i << 4) + lr4;
#pragma unroll
      for (int q = 0; q < 4; ++q) {
        const int p = row0 + rl + q;
        if (p < gend) hid[((size_t)p << 11) + c] = f2bf(fmaxf(acc[i][j][q] + bias, 0.f));
      }
    }
  }
}

// ---------------- GEMM2: out[perm[p]][c] = hid[p] @ [ew2[e]; uw2] + eb2[e] + ub2 ----------------
__global__ __launch_bounds__(256) void gemm2_kernel(
    const u16* __restrict__ hid, const u16* __restrict__ ew2t,
    const u16* __restrict__ uw2t, const float* __restrict__ eb2,
    const float* __restrict__ ub2, const int* __restrict__ meta,
    const int* __restrict__ perm, float* __restrict__ out) {
  const int nt = meta[25];
  // XCD-chunked, mt-major: grid 1080 = 8 jt x 135 mt
  const int pb = blockIdx.x;
  const int L = (pb & 7) * 135 + (pb >> 3);
  const int mt = L >> 3;
  const int jt = L & 7;
  if (mt >= nt) return;
  const int e = meta[32 + mt], row0 = meta[192 + mt], gend = meta[352 + mt];
  const int n0 = jt << 7;

  __shared__ u16 sA[2][128 * 32];
  __shared__ u16 sB[2][128 * 32];

  const int tid = threadIdx.x;
  const int lane = tid & 63;
  const int wave = tid >> 6;
  const int wr = (wave >> 1) << 6;
  const int wc = (wave & 1) << 6;

  const int smrow = tid >> 2;
  const int skoff = (((tid & 3) ^ ((tid >> 3) & 3)) << 3);
  const u16* ap0 = hid + (((size_t)(row0 + smrow)) << 11) + skoff;
  const u16* ap1 = hid + (((size_t)(row0 + smrow + 64)) << 11) + skoff;
  const u16* ebase = ew2t + ((size_t)e << 20);
  const size_t brow0 = (((size_t)(n0 + smrow)) << 10) + skoff;
  const size_t brow1 = (((size_t)(n0 + smrow + 64)) << 10) + skoff;
  const int ldsoff = wave << 10;

  f32x4 acc[4][4];
#pragma unroll
  for (int i = 0; i < 4; ++i)
#pragma unroll
    for (int j = 0; j < 4; ++j) acc[i][j] = (f32x4){0.f, 0.f, 0.f, 0.f};

  gload16(ap0, (char*)sA[0] + ldsoff);
  gload16(ap1, (char*)sA[0] + 4096 + ldsoff);
  gload16(ebase + brow0, (char*)sB[0] + ldsoff);
  gload16(ebase + brow1, (char*)sB[0] + 4096 + ldsoff);

  const int sl = (((lane >> 4) ^ ((lane >> 1) & 3)) << 3);
  const int afrag = (wr + (lane & 15)) * 32 + sl;
  const int bfrag = (wc + (lane & 15)) * 32 + sl;

#pragma unroll
  for (int ks = 0; ks < 64; ++ks) {
    const int buf = ks & 1;
    __syncthreads();
    if (ks + 1 < 64) {
      const int k1 = (ks + 1) << 5;
      const u16* bb = (k1 < 1024) ? ebase : uw2t;
      const int kk = k1 & 1023;
      gload16(ap0 + k1, (char*)sA[buf ^ 1] + ldsoff);
      gload16(ap1 + k1, (char*)sA[buf ^ 1] + 4096 + ldsoff);
      gload16(bb + brow0 + kk, (char*)sB[buf ^ 1] + ldsoff);
      gload16(bb + brow1 + kk, (char*)sB[buf ^ 1] + 4096 + ldsoff);
    }
    bf16x8 av[4], bv[4];
#pragma unroll
    for (int f = 0; f < 4; ++f) {
      av[f] = *(const bf16x8*)&sA[buf][afrag + f * 512];
      bv[f] = *(const bf16x8*)&sB[buf][bfrag + f * 512];
    }
#pragma unroll
    for (int i = 0; i < 4; ++i)
#pragma unroll
      for (int j = 0; j < 4; ++j)
        acc[i][j] = __builtin_amdgcn_mfma_f32_16x16x32_bf16(av[i], bv[j], acc[i][j], 0, 0, 0);
  }

  const int lc = lane & 15;
  const int lr4 = (lane >> 4) << 2;
#pragma unroll
  for (int j = 0; j < 4; ++j) {
    const int c = n0 + wc + (j << 4) + lc;
    const float bias = eb2[(e << 10) + c] + ub2[c];
#pragma unroll
    for (int i = 0; i < 4; ++i) {
      const int rl = wr + (i << 4) + lr4;
#pragma unroll
      for (int q = 0; q < 4; ++q) {
        const int p = row0 + rl + q;
        if (p < gend) out[((size_t)perm[p] << 10) + c] = acc[i][j][q] + bias;
      }
    }
  }
}

extern "C" void kernel_launch(void* const* d_in, const int* in_sizes, int n_in,
                              void* d_out, int out_size, void* d_ws, size_t ws_size,
                              hipStream_t stream) {
  const float* x   = (const float*)d_in[0];
  const float* ue  = (const float*)d_in[1];
  const float* sw1 = (const float*)d_in[2];
  const float* sb1 = (const float*)d_in[3];
  const float* sw2 = (const float*)d_in[4];
  const float* sb2 = (const float*)d_in[5];
  const float* ew1 = (const float*)d_in[6];
  const float* eb1 = (const float*)d_in[7];
  const float* ew2 = (const float*)d_in[8];
  const float* eb2 = (const float*)d_in[9];
  const float* uw1 = (const float*)d_in[10];
  const float* ub1 = (const float*)d_in[11];
  const float* uw2 = (const float*)d_in[12];
  const float* ub2 = (const float*)d_in[13];
  float* out = (float*)d_out;

  char* w = (char*)d_ws;
  int* meta = (int*)w;    w += 4096;
  int* routes = (int*)w;  w += NTOK * 4;
  int* perm = (int*)w;    w += NTOK * 4;
  char* region = w;
  u16* xg   = (u16*)region;                                             // 33,816,576 B
  u16* ew1t = (u16*)(region + 33816576ull);                             // 16 MiB
  u16* ew2t = (u16*)(region + 33816576ull + 16777216ull);               // 16 MiB
  u16* uw1t = (u16*)(region + 33816576ull + 2 * 16777216ull);           // 2 MiB
  u16* uw2t = (u16*)(region + 33816576ull + 2 * 16777216ull + 2097152ull);
  u16* hid  = (u16*)(region + 33816576ull + 2 * 16777216ull + 2 * 2097152ull);  // 67,633,152 B
  const size_t region_sz = 33816576ull + 2 * 16777216ull + 2 * 2097152ull + 67633152ull;
  // router-phase aliases live in the (dead-until-gemm1) hid region / xg region:
  _Float16* aP     = (_Float16*)(region + 33816576ull + 2 * 16777216ull + 2 * 2097152ull);
  float* hidden32  = (float*)region;
  _Float16* bP     = (_Float16*)(region + 16777216ull);
  if (135168ull + region_sz > ws_size) return;

  hipMemsetAsync(meta, 0, 4096, stream);
  prep_kernel<<<12864, 256, 0, stream>>>(ue, aP, sw1, bP, ew1, ew2, uw1, uw2,
                                         ew1t, ew2t, uw1t, uw2t);
  rgemm_kernel<<<256, 256, 0, stream>>>(aP, bP, sb1, hidden32);
  logits_kernel<<<NTOK / 32, 256, 0, stream>>>(hidden32, sw2, sb2, routes, meta);
  perm_kernel<<<NTOK / 256, 256, 0, stream>>>(routes, meta, perm);
  gatherx_kernel<<<(NTOK * 128) / 256, 256, 0, stream>>>(x, perm, xg);
  gemm1_kernel<<<2160, 256, 0, stream>>>(xg, ew1t, uw1t, eb1, ub1, meta, hid);
  gemm2_kernel<<<1080, 256, 0, stream>>>(hid, ew2t, uw2t, eb2, ub2, meta, perm, out);
}

// Round 11
// 583.191 us; speedup vs baseline: 2.2954x; 1.0681x over previous
//
#include <hip/hip_runtime.h>
#include <stdint.h>

#define NTOK 16384
#define HD   1024
#define SD   256
#define NE   8

typedef short bf16x8 __attribute__((ext_vector_type(8)));
typedef _Float16 f16x8 __attribute__((ext_vector_type(8)));
typedef float f32x4 __attribute__((ext_vector_type(4)));
typedef unsigned short u16;
typedef unsigned short u16x8 __attribute__((ext_vector_type(8)));

__device__ __forceinline__ u16 f2bf(float f) {
  union { float f; unsigned u; } v; v.f = f;
  return (u16)((v.u + 0x7fffu + ((v.u >> 16) & 1u)) >> 16);
}

__device__ __forceinline__ void gload16(const void* g, void* l) {
  __builtin_amdgcn_global_load_lds((const __attribute__((address_space(1))) void*)g,
                                   (__attribute__((address_space(3))) void*)l,
                                   16, 0, 0);
}

// meta layout (ints): [0..7] counts, [8..15] cursors, [16..24] offsets,
// [25] ntiles, [26] logits-done counter, [32..191] tile_e, [192..351] tile_row0,
// [352..511] tile_end

// LDS chunk-XOR swizzle (all 3 GEMMs): tile rows are 32 u16 = 4 chunks of 16B.
// LDS[row][slot] holds global chunk (slot ^ ((row>>1)&3)). Staging lane l reads
// global chunk (l&3)^((l>>3)&3) of row l>>2 -> each 4-lane group still covers
// one contiguous 64B row segment (VMEM coalescing identical) and the linear
// gload_lds dest produces the swizzled layout. Fragment read lane l uses slot
// (l>>4)^((l>>1)&3): conflict-free ds_read_b128 (verified: conflicts 8.7M -> 0).
// K-loops fully unrolled (r8: -25us).
// r10 LESSON: rgemm at grid 256 = 1 block/CU loses inter-block TLP (-13us);
// keep grid 512 (64-col tiles, 2 blocks/CU).
// r9 LESSON: do NOT fuse the per-token atomic into gatherx (898us latency chain).
// r11: gemm1 epilogue LDS-staged -> 256B contiguous stores (WRITE_SIZE was
// 137MB for a 64MB output: 32B chunks vs 128B TCC lines = 2.14x amplification).

// ---------------- Fused prep: aprep (8192 blk) + bprep (64 blk) + tconv (4608 blk) ----------------
__global__ __launch_bounds__(256) void prep_kernel(
    const float* __restrict__ ue, _Float16* __restrict__ aP,
    const float* __restrict__ sw1, _Float16* __restrict__ bP,
    const float* __restrict__ ew1, const float* __restrict__ ew2,
    const float* __restrict__ uw1, const float* __restrict__ uw2,
    u16* __restrict__ ew1t, u16* __restrict__ ew2t,
    u16* __restrict__ uw1t, u16* __restrict__ uw2t) {
  const int bid = blockIdx.x;
  const int tid = threadIdx.x;
  if (bid < 8192) {
    // --- aprep: ue f32 -> A' = [hi | lo] fp16, row stride 2048 ---
    const int t = bid * 256 + tid;
    const int p = t >> 7;
    const int h = (t & 127) << 3;
    const float* s = ue + ((size_t)p << 10) + h;
    const float4 a = *(const float4*)s;
    const float4 b = *(const float4*)(s + 4);
    float v[8] = {a.x, a.y, a.z, a.w, b.x, b.y, b.z, b.w};
    f16x8 hi, lo;
#pragma unroll
    for (int j = 0; j < 8; ++j) {
      const _Float16 h16 = (_Float16)v[j];
      hi[j] = h16;
      lo[j] = (_Float16)(v[j] - (float)h16);
    }
    _Float16* d = aP + ((size_t)p << 11) + h;
    *(f16x8*)d = hi;
    *(f16x8*)(d + 1024) = lo;
    return;
  }
  __shared__ float tb[64][65];
  if (bid < 8256) {
    // --- bprep: sw1 [1024][256] f32 -> B' [256][3072] fp16 = [hi|lo|hi] ---
    const int b = bid - 8192;
    const int c0 = (b & 3) << 6;
    const int r0 = (b >> 2) << 6;
    {
      const int lr = tid >> 2, q = (tid & 3) << 4;
      const float* s = sw1 + (size_t)(r0 + lr) * SD + c0 + q;
#pragma unroll
      for (int j = 0; j < 16; j += 4) {
        const float4 v = *(const float4*)(s + j);
        tb[lr][q + j] = v.x; tb[lr][q + j + 1] = v.y;
        tb[lr][q + j + 2] = v.z; tb[lr][q + j + 3] = v.w;
      }
    }
    __syncthreads();
    const int lc = tid >> 2, rq = (tid & 3) << 4;
    f16x8 hi0, hi1, lo0, lo1;
#pragma unroll
    for (int j = 0; j < 8; ++j) {
      const float v0 = tb[rq + j][lc];
      const _Float16 h0 = (_Float16)v0;
      hi0[j] = h0; lo0[j] = (_Float16)(v0 - (float)h0);
      const float v1 = tb[rq + 8 + j][lc];
      const _Float16 h1 = (_Float16)v1;
      hi1[j] = h1; lo1[j] = (_Float16)(v1 - (float)h1);
    }
    _Float16* d = bP + (size_t)(c0 + lc) * 3072 + r0 + rq;
    *(f16x8*)d = hi0;           *(f16x8*)(d + 8) = hi1;
    *(f16x8*)(d + 1024) = lo0;  *(f16x8*)(d + 1032) = lo1;
    *(f16x8*)(d + 2048) = hi0;  *(f16x8*)(d + 2056) = hi1;
    return;
  }
  // --- tconv: transpose+convert 1024x1024 f32 -> bf16, 18 matrices ---
  const int c = bid - 8256;
  const int m = c >> 8;
  const int t2 = c & 255;
  const int c0 = (t2 & 15) << 6;
  const int r0 = (t2 >> 4) << 6;
  const size_t msz = (size_t)HD * HD;
  const float* src; u16* dst;
  if (m < 8)       { src = ew1 + (size_t)m * msz;       dst = ew1t + (size_t)m * msz; }
  else if (m < 16) { src = ew2 + (size_t)(m - 8) * msz; dst = ew2t + (size_t)(m - 8) * msz; }
  else if (m == 16){ src = uw1;                          dst = uw1t; }
  else             { src = uw2;                          dst = uw2t; }
  {
    const int lr = tid >> 2, q = (tid & 3) << 4;
    const float* s = src + (size_t)(r0 + lr) * HD + c0 + q;
#pragma unroll
    for (int j = 0; j < 16; j += 4) {
      const float4 v = *(const float4*)(s + j);
      tb[lr][q + j] = v.x; tb[lr][q + j + 1] = v.y;
      tb[lr][q + j + 2] = v.z; tb[lr][q + j + 3] = v.w;
    }
  }
  __syncthreads();
  {
    const int lc = tid >> 2, rq = (tid & 3) << 4;
    u16x8 o0, o1;
#pragma unroll
    for (int j = 0; j < 8; ++j) o0[j] = f2bf(tb[rq + j][lc]);
#pragma unroll
    for (int j = 0; j < 8; ++j) o1[j] = f2bf(tb[rq + 8 + j][lc]);
    u16* d = dst + (size_t)(c0 + lc) * HD + r0 + rq;
    *(u16x8*)d = o0;
    *(u16x8*)(d + 8) = o1;
  }
}

// ---------------- Router GEMM: hidden[p][s] = relu(3-term hi/lo fp16 MFMA + sb1), f32 out ----------------
__global__ __launch_bounds__(256) void rgemm_kernel(
    const _Float16* __restrict__ aP, const _Float16* __restrict__ bP,
    const float* __restrict__ sb1, float* __restrict__ hidden) {
  const int p = blockIdx.x;
  const int L = (p & 7) * 64 + (p >> 3);
  const int jt = L & 3;           // 64-col tile
  const int row0 = (L >> 2) << 7; // 128-row tile

  __shared__ _Float16 sA[2][128 * 32];
  __shared__ _Float16 sB[2][64 * 32];

  const int tid = threadIdx.x, lane = tid & 63, wave = tid >> 6;
  const int wr = (wave >> 1) << 6, wc = (wave & 1) << 5;
  const int smrow = tid >> 2, skoff = (((tid & 3) ^ ((tid >> 3) & 3)) << 3);
  const _Float16* ar0 = aP + ((size_t)(row0 + smrow) << 11) + skoff;
  const _Float16* ar1 = aP + ((size_t)(row0 + smrow + 64) << 11) + skoff;
  const _Float16* br  = bP + (size_t)((jt << 6) + smrow) * 3072 + skoff;
  const int ldsoff = wave << 10;

  f32x4 acc[4][2];
#pragma unroll
  for (int i = 0; i < 4; ++i)
#pragma unroll
    for (int j = 0; j < 2; ++j) acc[i][j] = (f32x4){0.f, 0.f, 0.f, 0.f};

  gload16(ar0, (char*)sA[0] + ldsoff);
  gload16(ar1, (char*)sA[0] + 4096 + ldsoff);
  gload16(br,  (char*)sB[0] + ldsoff);

  const int sl = (((lane >> 4) ^ ((lane >> 1) & 3)) << 3);
  const int afrag = (wr + (lane & 15)) * 32 + sl;
  const int bfrag = (wc + (lane & 15)) * 32 + sl;

#pragma unroll
  for (int ks = 0; ks < 96; ++ks) {
    const int buf = ks & 1;
    __syncthreads();
    if (ks + 1 < 96) {
      const int k1 = ks + 1;
      const int pa = (k1 < 64) ? ((k1 & 31) << 5) : (1024 + ((k1 - 64) << 5));
      gload16(ar0 + pa, (char*)sA[buf ^ 1] + ldsoff);
      gload16(ar1 + pa, (char*)sA[buf ^ 1] + 4096 + ldsoff);
      gload16(br + (k1 << 5), (char*)sB[buf ^ 1] + ldsoff);
    }
    f16x8 av[4], bv[2];
#pragma unroll
    for (int f = 0; f < 4; ++f) av[f] = *(const f16x8*)&sA[buf][afrag + f * 512];
#pragma unroll
    for (int f = 0; f < 2; ++f) bv[f] = *(const f16x8*)&sB[buf][bfrag + f * 512];
#pragma unroll
    for (int i = 0; i < 4; ++i)
#pragma unroll
      for (int j = 0; j < 2; ++j)
        acc[i][j] = __builtin_amdgcn_mfma_f32_16x16x32_f16(av[i], bv[j], acc[i][j], 0, 0, 0);
  }

  const int lc = lane & 15, lr4 = (lane >> 4) << 2;
#pragma unroll
  for (int j = 0; j < 2; ++j) {
    const int c = (jt << 6) + wc + (j << 4) + lc;
    const float bias = sb1[c];
#pragma unroll
    for (int i = 0; i < 4; ++i) {
      const int rl = wr + (i << 4) + lr4;
#pragma unroll
      for (int q = 0; q < 4; ++q)
        hidden[((size_t)(row0 + rl + q) << 8) + c] = fmaxf(acc[i][j][q] + bias, 0.f);
    }
  }
}

// ---------------- Logits layer-2 + argmax + histogram + fused scan (last block) ----------------
__global__ __launch_bounds__(256) void logits_kernel(
    const float* __restrict__ hidden, const float* __restrict__ sw2,
    const float* __restrict__ sb2, int* __restrict__ routes, int* meta) {
  __shared__ float logl[32][8];
  const int tid = threadIdx.x;
  const int tok0 = blockIdx.x << 5;
  const int tl = tid >> 3, e2 = tid & 7;
  const float* hp = hidden + ((size_t)(tok0 + tl) << 8);
  float a0 = 0.f, a1 = 0.f, a2 = 0.f, a3 = 0.f;
  for (int q = 0; q < SD; q += 8) {
    const float4 h0 = *(const float4*)&hp[q];
    const float4 h1 = *(const float4*)&hp[q + 4];
    a0 = fmaf(h0.x, sw2[((q + 0) << 3) + e2], a0);
    a1 = fmaf(h0.y, sw2[((q + 1) << 3) + e2], a1);
    a2 = fmaf(h0.z, sw2[((q + 2) << 3) + e2], a2);
    a3 = fmaf(h0.w, sw2[((q + 3) << 3) + e2], a3);
    a0 = fmaf(h1.x, sw2[((q + 4) << 3) + e2], a0);
    a1 = fmaf(h1.y, sw2[((q + 5) << 3) + e2], a1);
    a2 = fmaf(h1.z, sw2[((q + 6) << 3) + e2], a2);
    a3 = fmaf(h1.w, sw2[((q + 7) << 3) + e2], a3);
  }
  logl[tl][e2] = (a0 + a1) + (a2 + a3) + sb2[e2];
  __syncthreads();
  if (tid < 32) {
    float best = logl[tid][0]; int be = 0;
#pragma unroll
    for (int e = 1; e < 8; ++e) {
      const float v = logl[tid][e];
      if (v > best) { best = v; be = e; }
    }
    routes[tok0 + tid] = be;
    atomicAdd(&meta[be], 1);
  }
  // last-block-done: fused scan (replaces scan_kernel launch)
  __syncthreads();
  if (tid == 0) {
    __threadfence();
    const int done = atomicAdd(&meta[26], 1);
    if (done == (int)gridDim.x - 1) {
      int cnt[NE];
#pragma unroll
      for (int e = 0; e < NE; ++e) cnt[e] = atomicAdd(&meta[e], 0);
      int off = 0;
      for (int e = 0; e < NE; ++e) { meta[16 + e] = off; off += cnt[e]; }
      meta[24] = off;
      int nt = 0;
      for (int e = 0; e < NE; ++e) {
        const int s = meta[16 + e], en = meta[16 + e + 1];
        for (int r0 = s; r0 < en; r0 += 128) {
          meta[32 + nt] = e; meta[192 + nt] = r0; meta[352 + nt] = en; ++nt;
        }
      }
      meta[25] = nt;
      __threadfence();
    }
  }
}

// ---------------- Build permutation (token -> grouped position) ----------------
__global__ void perm_kernel(const int* __restrict__ routes, int* meta, int* __restrict__ perm) {
  const int b = blockIdx.x * 256 + threadIdx.x;
  const int r = routes[b];
  const int pos = meta[16 + r] + atomicAdd(&meta[8 + r], 1);
  perm[pos] = b;
}

// ---------------- Gather x rows into grouped order, f32 -> bf16 ----------------
__global__ __launch_bounds__(256) void gatherx_kernel(
    const float* __restrict__ x, const int* __restrict__ perm, u16* __restrict__ xg) {
  const int t = blockIdx.x * 256 + threadIdx.x;
  const int p = t >> 7;
  const int j = (t & 127) << 3;
  const int tok = perm[p];
  const float* s = &x[((size_t)tok << 10) + j];
  const float4 a = *(const float4*)s;
  const float4 b = *(const float4*)(s + 4);
  u16x8 o;
  o[0] = f2bf(a.x); o[1] = f2bf(a.y); o[2] = f2bf(a.z); o[3] = f2bf(a.w);
  o[4] = f2bf(b.x); o[5] = f2bf(b.y); o[6] = f2bf(b.z); o[7] = f2bf(b.w);
  *(u16x8*)&xg[((size_t)p << 10) + j] = o;
}

// ---------------- GEMM1: hid[p][0:2048] = relu(xg[p] @ [ew1[e] | uw1] + eb1[e]/ub1) ----------------
__global__ __launch_bounds__(256) void gemm1_kernel(
    const u16* __restrict__ xg, const u16* __restrict__ ew1t,
    const u16* __restrict__ uw1t, const float* __restrict__ eb1,
    const float* __restrict__ ub1, const int* __restrict__ meta,
    u16* __restrict__ hid) {
  const int nt = meta[25];
  // XCD-chunked, mt-major: grid 2160 = 16 jt x 135 mt
  const int pb = blockIdx.x;
  const int L = (pb & 7) * 270 + (pb >> 3);
  const int mt = L >> 4;
  const int jt = L & 15;
  if (mt >= nt) return;
  const int e = meta[32 + mt], row0 = meta[192 + mt], gend = meta[352 + mt];
  const u16* wbase = (jt < 8)
      ? ew1t + ((size_t)e << 20) + ((size_t)(jt << 7) << 10)
      : uw1t + ((size_t)((jt - 8) << 7) << 10);

  // 32KB unified LDS: K-loop uses sA[2][4096] + sB[2][4096]; epilogue reuses
  // the whole 16384-u16 block as a [128][128] output tile.
  __shared__ u16 smem[16384];
  u16 (*sA)[4096] = (u16(*)[4096])smem;
  u16 (*sB)[4096] = (u16(*)[4096])(smem + 8192);

  const int tid = threadIdx.x;
  const int lane = tid & 63;
  const int wave = tid >> 6;
  const int wr = (wave >> 1) << 6;
  const int wc = (wave & 1) << 6;

  const int smrow = tid >> 2;
  const int skoff = (((tid & 3) ^ ((tid >> 3) & 3)) << 3);
  const u16* ap0 = xg + (((size_t)(row0 + smrow)) << 10) + skoff;
  const u16* ap1 = xg + (((size_t)(row0 + smrow + 64)) << 10) + skoff;
  const u16* bp0 = wbase + (((size_t)smrow) << 10) + skoff;
  const u16* bp1 = wbase + (((size_t)(smrow + 64)) << 10) + skoff;
  const int ldsoff = wave << 10;

  f32x4 acc[4][4];
#pragma unroll
  for (int i = 0; i < 4; ++i)
#pragma unroll
    for (int j = 0; j < 4; ++j) acc[i][j] = (f32x4){0.f, 0.f, 0.f, 0.f};

  gload16(ap0, (char*)sA[0] + ldsoff);
  gload16(ap1, (char*)sA[0] + 4096 + ldsoff);
  gload16(bp0, (char*)sB[0] + ldsoff);
  gload16(bp1, (char*)sB[0] + 4096 + ldsoff);

  const int sl = (((lane >> 4) ^ ((lane >> 1) & 3)) << 3);
  const int afrag = (wr + (lane & 15)) * 32 + sl;
  const int bfrag = (wc + (lane & 15)) * 32 + sl;

#pragma unroll
  for (int ks = 0; ks < 32; ++ks) {
    const int buf = ks & 1;
    __syncthreads();
    if (ks + 1 < 32) {
      const int k1 = (ks + 1) << 5;
      gload16(ap0 + k1, (char*)sA[buf ^ 1] + ldsoff);
      gload16(ap1 + k1, (char*)sA[buf ^ 1] + 4096 + ldsoff);
      gload16(bp0 + k1, (char*)sB[buf ^ 1] + ldsoff);
      gload16(bp1 + k1, (char*)sB[buf ^ 1] + 4096 + ldsoff);
    }
    bf16x8 av[4], bv[4];
#pragma unroll
    for (int f = 0; f < 4; ++f) {
      av[f] = *(const bf16x8*)&sA[buf][afrag + f * 512];
      bv[f] = *(const bf16x8*)&sB[buf][bfrag + f * 512];
    }
#pragma unroll
    for (int i = 0; i < 4; ++i)
#pragma unroll
      for (int j = 0; j < 4; ++j)
        acc[i][j] = __builtin_amdgcn_mfma_f32_16x16x32_bf16(av[i], bv[j], acc[i][j], 0, 0, 0);
  }

  // --- epilogue: bias+relu+cvt -> LDS tile, then 256B-contiguous stores ---
  __syncthreads();   // K-loop LDS reads complete; smem is now reusable
  {
    const int lc = lane & 15;
    const int lr4 = (lane >> 4) << 2;
#pragma unroll
    for (int j = 0; j < 4; ++j) {
      const int c = wc + (j << 4) + lc;           // local col 0..127
      const int gc = (jt << 7) + c;
      const float bias = (gc < 1024) ? eb1[(e << 10) + gc] : ub1[gc - 1024];
#pragma unroll
      for (int i = 0; i < 4; ++i) {
        const int rl = wr + (i << 4) + lr4;
#pragma unroll
        for (int q = 0; q < 4; ++q)
          smem[(rl + q) * 128 + c] = f2bf(fmaxf(acc[i][j][q] + bias, 0.f));
      }
    }
  }
  __syncthreads();
  {
    // per instruction: 4 rows x 256B fully-contiguous global stores
    const int l16 = lane & 15, rg = lane >> 4;
#pragma unroll
    for (int it = 0; it < 8; ++it) {
      const int lr = (wave << 5) + (it << 2) + rg;   // local row 0..127
      const int p = row0 + lr;
      const u16x8 v = *(const u16x8*)&smem[lr * 128 + (l16 << 3)];
      if (p < gend)
        *(u16x8*)&hid[((size_t)p << 11) + (jt << 7) + (l16 << 3)] = v;
    }
  }
}

// ---------------- GEMM2: out[perm[p]][c] = hid[p] @ [ew2[e]; uw2] + eb2[e] + ub2 ----------------
__global__ __launch_bounds__(256) void gemm2_kernel(
    const u16* __restrict__ hid, const u16* __restrict__ ew2t,
    const u16* __restrict__ uw2t, const float* __restrict__ eb2,
    const float* __restrict__ ub2, const int* __restrict__ meta,
    const int* __restrict__ perm, float* __restrict__ out) {
  const int nt = meta[25];
  // XCD-chunked, mt-major: grid 1080 = 8 jt x 135 mt
  const int pb = blockIdx.x;
  const int L = (pb & 7) * 135 + (pb >> 3);
  const int mt = L >> 3;
  const int jt = L & 7;
  if (mt >= nt) return;
  const int e = meta[32 + mt], row0 = meta[192 + mt], gend = meta[352 + mt];
  const int n0 = jt << 7;

  __shared__ u16 sA[2][128 * 32];
  __shared__ u16 sB[2][128 * 32];

  const int tid = threadIdx.x;
  const int lane = tid & 63;
  const int wave = tid >> 6;
  const int wr = (wave >> 1) << 6;
  const int wc = (wave & 1) << 6;

  const int smrow = tid >> 2;
  const int skoff = (((tid & 3) ^ ((tid >> 3) & 3)) << 3);
  const u16* ap0 = hid + (((size_t)(row0 + smrow)) << 11) + skoff;
  const u16* ap1 = hid + (((size_t)(row0 + smrow + 64)) << 11) + skoff;
  const u16* ebase = ew2t + ((size_t)e << 20);
  const size_t brow0 = (((size_t)(n0 + smrow)) << 10) + skoff;
  const size_t brow1 = (((size_t)(n0 + smrow + 64)) << 10) + skoff;
  const int ldsoff = wave << 10;

  f32x4 acc[4][4];
#pragma unroll
  for (int i = 0; i < 4; ++i)
#pragma unroll
    for (int j = 0; j < 4; ++j) acc[i][j] = (f32x4){0.f, 0.f, 0.f, 0.f};

  gload16(ap0, (char*)sA[0] + ldsoff);
  gload16(ap1, (char*)sA[0] + 4096 + ldsoff);
  gload16(ebase + brow0, (char*)sB[0] + ldsoff);
  gload16(ebase + brow1, (char*)sB[0] + 4096 + ldsoff);

  const int sl = (((lane >> 4) ^ ((lane >> 1) & 3)) << 3);
  const int afrag = (wr + (lane & 15)) * 32 + sl;
  const int bfrag = (wc + (lane & 15)) * 32 + sl;

#pragma unroll
  for (int ks = 0; ks < 64; ++ks) {
    const int buf = ks & 1;
    __syncthreads();
    if (ks + 1 < 64) {
      const int k1 = (ks + 1) << 5;
      const u16* bb = (k1 < 1024) ? ebase : uw2t;
      const int kk = k1 & 1023;
      gload16(ap0 + k1, (char*)sA[buf ^ 1] + ldsoff);
      gload16(ap1 + k1, (char*)sA[buf ^ 1] + 4096 + ldsoff);
      gload16(bb + brow0 + kk, (char*)sB[buf ^ 1] + ldsoff);
      gload16(bb + brow1 + kk, (char*)sB[buf ^ 1] + 4096 + ldsoff);
    }
    bf16x8 av[4], bv[4];
#pragma unroll
    for (int f = 0; f < 4; ++f) {
      av[f] = *(const bf16x8*)&sA[buf][afrag + f * 512];
      bv[f] = *(const bf16x8*)&sB[buf][bfrag + f * 512];
    }
#pragma unroll
    for (int i = 0; i < 4; ++i)
#pragma unroll
      for (int j = 0; j < 4; ++j)
        acc[i][j] = __builtin_amdgcn_mfma_f32_16x16x32_bf16(av[i], bv[j], acc[i][j], 0, 0, 0);
  }

  const int lc = lane & 15;
  const int lr4 = (lane >> 4) << 2;
#pragma unroll
  for (int j = 0; j < 4; ++j) {
    const int c = n0 + wc + (j << 4) + lc;
    const float bias = eb2[(e << 10) + c] + ub2[c];
#pragma unroll
    for (int i = 0; i < 4; ++i) {
      const int rl = wr + (i << 4) + lr4;
#pragma unroll
      for (int q = 0; q < 4; ++q) {
        const int p = row0 + rl + q;
        if (p < gend) out[((size_t)perm[p] << 10) + c] = acc[i][j][q] + bias;
      }
    }
  }
}

extern "C" void kernel_launch(void* const* d_in, const int* in_sizes, int n_in,
                              void* d_out, int out_size, void* d_ws, size_t ws_size,
                              hipStream_t stream) {
  const float* x   = (const float*)d_in[0];
  const float* ue  = (const float*)d_in[1];
  const float* sw1 = (const float*)d_in[2];
  const float* sb1 = (const float*)d_in[3];
  const float* sw2 = (const float*)d_in[4];
  const float* sb2 = (const float*)d_in[5];
  const float* ew1 = (const float*)d_in[6];
  const float* eb1 = (const float*)d_in[7];
  const float* ew2 = (const float*)d_in[8];
  const float* eb2 = (const float*)d_in[9];
  const float* uw1 = (const float*)d_in[10];
  const float* ub1 = (const float*)d_in[11];
  const float* uw2 = (const float*)d_in[12];
  const float* ub2 = (const float*)d_in[13];
  float* out = (float*)d_out;

  char* w = (char*)d_ws;
  int* meta = (int*)w;    w += 4096;
  int* routes = (int*)w;  w += NTOK * 4;
  int* perm = (int*)w;    w += NTOK * 4;
  char* region = w;
  u16* xg   = (u16*)region;                                             // 33,816,576 B
  u16* ew1t = (u16*)(region + 33816576ull);                             // 16 MiB
  u16* ew2t = (u16*)(region + 33816576ull + 16777216ull);               // 16 MiB
  u16* uw1t = (u16*)(region + 33816576ull + 2 * 16777216ull);           // 2 MiB
  u16* uw2t = (u16*)(region + 33816576ull + 2 * 16777216ull + 2097152ull);
  u16* hid  = (u16*)(region + 33816576ull + 2 * 16777216ull + 2 * 2097152ull);  // 67,633,152 B
  const size_t region_sz = 33816576ull + 2 * 16777216ull + 2 * 2097152ull + 67633152ull;
  // router-phase aliases live in the (dead-until-gemm1) hid region / xg region:
  _Float16* aP     = (_Float16*)(region + 33816576ull + 2 * 16777216ull + 2 * 2097152ull);
  float* hidden32  = (float*)region;
  _Float16* bP     = (_Float16*)(region + 16777216ull);
  if (135168ull + region_sz > ws_size) return;

  hipMemsetAsync(meta, 0, 4096, stream);
  prep_kernel<<<12864, 256, 0, stream>>>(ue, aP, sw1, bP, ew1, ew2, uw1, uw2,
                                         ew1t, ew2t, uw1t, uw2t);
  rgemm_kernel<<<512, 256, 0, stream>>>(aP, bP, sb1, hidden32);
  logits_kernel<<<NTOK / 32, 256, 0, stream>>>(hidden32, sw2, sb2, routes, meta);
  perm_kernel<<<NTOK / 256, 256, 0, stream>>>(routes, meta, perm);
  gatherx_kernel<<<(NTOK * 128) / 256, 256, 0, stream>>>(x, perm, xg);
  gemm1_kernel<<<2160, 256, 0, stream>>>(xg, ew1t, uw1t, eb1, ub1, meta, hid);
  gemm2_kernel<<<1080, 256, 0, stream>>>(hid, ew2t, uw2t, eb2, ub2, meta, perm, out);
}